// Round 13
// baseline (10025.428 us; speedup 1.0000x reference)
//
#include <hip/hip_runtime.h>
#include <math.h>

typedef __attribute__((ext_vector_type(8))) short bf16x8;
typedef __attribute__((ext_vector_type(4))) short short4v;
typedef __attribute__((ext_vector_type(4))) float f32x4;

#define SCALE 0.17677669529663687f  // 32^-0.5

__device__ __forceinline__ short f2bf(float f) {
  unsigned u = __builtin_bit_cast(unsigned, f);
  unsigned r = u + 0x7fffu + ((u >> 16) & 1u);
  return (short)(r >> 16);
}

// async global->LDS, 16B per lane (dest = wave-uniform base + lane*16)
__device__ __forceinline__ void gll16(const short* g, short* l) {
  __builtin_amdgcn_global_load_lds(
      (const __attribute__((address_space(1))) unsigned int*)g,
      (__attribute__((address_space(3))) unsigned int*)l, 16, 0, 0);
}

// ---------------- weight casts ----------------
__global__ __launch_bounds__(256) void cast_qkw_kernel(const float* __restrict__ src,
                                                       short* __restrict__ dst) {
  size_t i = (size_t)blockIdx.x * 256 + threadIdx.x;
  f32x4 v = *(const f32x4*)(src + i * 4);
  float sc = (i * 4 < (size_t)1024 * 1024) ? SCALE : 1.0f;  // q out-rows get scale
  short4v o;
#pragma unroll
  for (int j = 0; j < 4; ++j) o[j] = f2bf(v[j] * sc);
  *(short4v*)(dst + i * 4) = o;
}

__global__ __launch_bounds__(256) void cast_kernel(const float* __restrict__ src,
                                                   short* __restrict__ dst) {
  size_t i = (size_t)blockIdx.x * 256 + threadIdx.x;
  f32x4 v = *(const f32x4*)(src + i * 4);
  short4v o;
#pragma unroll
  for (int j = 0; j < 4; ++j) o[j] = f2bf(v[j]);
  *(short4v*)(dst + i * 4) = o;
}

// ---------------- LN1 + shift + window-partition ----------------
__global__ __launch_bounds__(256) void ln1_permute_kernel(
    const float* __restrict__ x,
    const float* __restrict__ g1, const float* __restrict__ b1,
    short* __restrict__ xnw) {
  int r = blockIdx.x;
  int b = r / 3136, rem = r % 3136;
  int wi = rem / 49, n = rem % 49;
  int hs = (wi >> 3) * 7 + n / 7, wsf = (wi & 7) * 7 + n % 7;
  int ho = hs + 3; if (ho >= 56) ho -= 56;
  int wo = wsf + 3; if (wo >= 56) wo -= 56;
  size_t src = ((size_t)b * 3136 + ho * 56 + wo) * 1024;
  int t = threadIdx.x;
  f32x4 xv = *(const f32x4*)(x + src + t * 4);
  float s = xv[0] + xv[1] + xv[2] + xv[3];
  float s2 = xv[0] * xv[0] + xv[1] * xv[1] + xv[2] * xv[2] + xv[3] * xv[3];
#pragma unroll
  for (int m = 1; m < 64; m <<= 1) { s += __shfl_xor(s, m); s2 += __shfl_xor(s2, m); }
  __shared__ float red[8];
  int w = t >> 6;
  if ((t & 63) == 0) { red[w * 2] = s; red[w * 2 + 1] = s2; }
  __syncthreads();
  float ts = red[0] + red[2] + red[4] + red[6];
  float ts2 = red[1] + red[3] + red[5] + red[7];
  float mu = ts * (1.0f / 1024.0f);
  float var = ts2 * (1.0f / 1024.0f) - mu * mu;
  float rs = rsqrtf(var + 1e-5f);
  short4v xo;
#pragma unroll
  for (int j = 0; j < 4; ++j) {
    int cc = t * 4 + j;
    xo[j] = f2bf((xv[j] - mu) * rs * g1[cc] + b1[cc]);
  }
  *(short4v*)(xnw + (size_t)r * 1024 + t * 4) = xo;
}

// ---------------- LN2 ----------------
__global__ __launch_bounds__(256) void ln2_kernel(const float* __restrict__ x2,
                                                  const float* __restrict__ g2,
                                                  const float* __restrict__ b2,
                                                  short* __restrict__ xn2) {
  int r = blockIdx.x;
  size_t src = (size_t)r * 1024;
  int t = threadIdx.x;
  f32x4 xv = *(const f32x4*)(x2 + src + t * 4);
  float s = xv[0] + xv[1] + xv[2] + xv[3];
  float s2 = xv[0] * xv[0] + xv[1] * xv[1] + xv[2] * xv[2] + xv[3] * xv[3];
#pragma unroll
  for (int m = 1; m < 64; m <<= 1) { s += __shfl_xor(s, m); s2 += __shfl_xor(s2, m); }
  __shared__ float red[8];
  int w = t >> 6;
  if ((t & 63) == 0) { red[w * 2] = s; red[w * 2 + 1] = s2; }
  __syncthreads();
  float ts = red[0] + red[2] + red[4] + red[6];
  float ts2 = red[1] + red[3] + red[5] + red[7];
  float mu = ts * (1.0f / 1024.0f);
  float var = ts2 * (1.0f / 1024.0f) - mu * mu;
  float rs = rsqrtf(var + 1e-5f);
  short4v xo;
#pragma unroll
  for (int j = 0; j < 4; ++j) {
    int cc = t * 4 + j;
    xo[j] = f2bf((xv[j] - mu) * rs * g2[cc] + b2[cc]);
  }
  *(short4v*)(xn2 + src + t * 4) = xo;
}

// ---------------- 256x256 persistent bf16 MFMA GEMM, BK=32 ring-2, 2 blocks/CU ----------------
// C[M,N] = A[M,K] @ Bt[N,K]^T. 512 threads = 8 waves (2M x 4N), per-wave 128x64 out.
// LDS 64 KiB: ring-2 x {A[256][32] 16KiB, B[256][32] 16KiB} -> 2 blocks/CU. The partner
// block's MFMA window covers this block's LDS-read drain (r12 model: reads+MFMA serialize
// within a lockstep block at ~50% each; cross-block slip provides the overlap).
// Phase sigma (db=sigma&1): STG(db^1,sigma+1); vmcnt(4); BAR1; 12 ds_reads(db); lgkm(2);
// 16 MFMA; lgkm(0); 16 MFMA; BAR2.  Audit: staged region confirmed collectively at next
// phase's vmcnt(4)+BAR1; WAR safe (reads drained at lgkm0 before BAR2, clobbering STG only
// after BAR2); prologue stages region0; persistent stream wraps tiles (rel>=NT -> next tile,
// clamped on last). st_16x32 swizzle via pre-swizzled global source + swizzled ds_read;
// fragment-base bit9 lane-constant -> all ds_reads base+imm.
// EPI: 0 = qk (bias, pre-scaled, bf16)  1 = proj (bias + shortcut, window->orig scatter, f32)
//      2 = fc1 (bias + tanh-gelu, bf16)  3 = fc2 (bias + residual, f32; add0 may alias out)
template <int EPI>
__global__ __launch_bounds__(512, 4) void gemmtb(const short* __restrict__ A,
                                                 const short* __restrict__ Bt,
                                                 const float* __restrict__ bias,
                                                 const float* __restrict__ add0,
                                                 void* __restrict__ out, int N, int K,
                                                 int ntm, int ntot) {
  __shared__ __align__(16) short lds[32768];  // 64 KiB
  char* basec = (char*)lds;
  int t = threadIdx.x;
  int l = t & 63;
  int w = t >> 6;
  int wm = w >> 2, wn = w & 3;
  int g = l >> 4, c = l & 15;
  int G = gridDim.x;
  // bijective XCD-chunked swizzle over the persistent grid
  int orig = blockIdx.x;
  int q = G >> 3, rr8 = G & 7, xcd = orig & 7, idx = orig >> 3;
  int tau = (xcd < rr8 ? xcd * (q + 1) : rr8 * (q + 1) + (xcd - rr8) * q) + idx;
  if (tau >= ntot) return;  // dead block (grid > ntot)
  int bx = tau % ntm, by = tau / ntm;
  int tauN = tau + G; if (tauN >= ntot) tauN = tau;
  int bxN = tauN % ntm, byN = tauN / ntm;
  const short* AbC = A + (size_t)bx * 256 * K;
  const short* BbC = Bt + (size_t)by * 256 * K;
  const short* AbN = A + (size_t)bxN * 256 * K;
  const short* BbN = Bt + (size_t)byN * 256 * K;
  // staging source offsets (pre-swizzled st_16x32 inverse); region = [256 rows][32 cols]
  int o0 = t * 16, o1 = 8192 + t * 16;
  int ol0 = o0 ^ (((o0 >> 9) & 1) << 5);
  int ol1 = o1 ^ (((o1 >> 9) & 1) << 5);
  size_t off0 = (size_t)(ol0 >> 6) * K + ((ol0 & 63) >> 1);
  size_t off1 = (size_t)(ol1 >> 6) * K + ((ol1 & 63) >> 1);
  int NT = K >> 5;  // K-tiles of 32 per output tile (pow2, even)
  // fragment read bases (swizzle bit9 lane-constant; db stride 32768, B offset 16384 safe)
  int labA = (wm * 128 + c) * 64 + g * 16; labA ^= ((labA >> 9) & 1) << 5;
  int labB = (wn * 64 + c) * 64 + g * 16;  labB ^= ((labB >> 9) & 1) << 5;
  const char* pA0 = basec + labA;
  const char* pA1 = pA0 + 32768;
  const char* pB0 = basec + 16384 + labB;
  const char* pB1 = pB0 + 32768;

  f32x4 acc[8][4] = {};
  bf16x8 af[8], bf4[4];

#define STG(sdb, rel)                                                   \
  do {                                                                  \
    int rl = (rel);                                                     \
    const short* bA = (rl < NT) ? AbC : AbN;                            \
    const short* bB = (rl < NT) ? BbC : BbN;                            \
    int tt = rl & (NT - 1);                                             \
    size_t kb = (size_t)tt * 32;                                        \
    short* rgA = (short*)(basec + (sdb) * 32768);                       \
    short* rgB = (short*)(basec + (sdb) * 32768 + 16384);               \
    gll16(bA + kb + off0, rgA + t * 8);                                 \
    gll16(bA + kb + off1, rgA + 4096 + t * 8);                          \
    gll16(bB + kb + off0, rgB + t * 8);                                 \
    gll16(bB + kb + off1, rgB + 4096 + t * 8);                          \
  } while (0)

#define DSR_A(db)                                                       \
  do {                                                                  \
    _Pragma("unroll") for (int m = 0; m < 8; ++m)                       \
      af[m] = *(const bf16x8*)(((db) ? pA1 : pA0) + m * 1024);          \
  } while (0)

#define DSR_B4(db)                                                      \
  do {                                                                  \
    _Pragma("unroll") for (int nf = 0; nf < 4; ++nf)                    \
      bf4[nf] = *(const bf16x8*)(((db) ? pB1 : pB0) + nf * 1024);       \
  } while (0)

#define SB __builtin_amdgcn_sched_barrier(0)

#define PHASE(db, rel)                                             \
  do {                                                             \
    STG((db) ^ 1, rel);                                            \
    asm volatile("s_waitcnt vmcnt(4)" ::: "memory");               \
    SB;                                                            \
    __builtin_amdgcn_s_barrier();                                  \
    SB;                                                            \
    DSR_A(db);                                                     \
    DSR_B4(db);                                                    \
    asm volatile("s_waitcnt lgkmcnt(2)" ::: "memory");             \
    SB;                                                            \
    __builtin_amdgcn_s_setprio(1);                                 \
    _Pragma("unroll") for (int m = 0; m < 8; ++m)                  \
      _Pragma("unroll") for (int n2 = 0; n2 < 2; ++n2)             \
        acc[m][n2] = __builtin_amdgcn_mfma_f32_16x16x32_bf16(      \
            af[m], bf4[n2], acc[m][n2], 0, 0, 0);                  \
    __builtin_amdgcn_s_setprio(0);                                 \
    SB;                                                            \
    asm volatile("s_waitcnt lgkmcnt(0)" ::: "memory");             \
    SB;                                                            \
    __builtin_amdgcn_s_setprio(1);                                 \
    _Pragma("unroll") for (int m = 0; m < 8; ++m)                  \
      _Pragma("unroll") for (int n2 = 2; n2 < 4; ++n2)             \
        acc[m][n2] = __builtin_amdgcn_mfma_f32_16x16x32_bf16(      \
            af[m], bf4[n2], acc[m][n2], 0, 0, 0);                  \
    __builtin_amdgcn_s_setprio(0);                                 \
    SB;                                                            \
    __builtin_amdgcn_s_barrier();                                  \
    SB;                                                            \
  } while (0)

  // prologue: stage region 0 with K-step 0
  STG(0, 0);

  while (true) {
    for (int s = 0; s < NT; s += 2) {
      PHASE(0, s + 1);
      PHASE(1, s + 2);
    }
    // ---- epilogue for current tile ----
    {
      int mb = bx * 256 + wm * 128;
      int nb = by * 256 + wn * 64;
#pragma unroll
      for (int m = 0; m < 8; ++m) {
#pragma unroll
        for (int i = 0; i < 4; ++i) {
          int row = mb + m * 16 + g * 4 + i;
          size_t orow = row;
          if (EPI == 1) {  // window order -> original order
            int bb = row / 3136, rem = row % 3136;
            int wi = rem / 49, n = rem % 49;
            int hs = (wi >> 3) * 7 + n / 7, wf = (wi & 7) * 7 + n % 7;
            int ho = hs + 3; if (ho >= 56) ho -= 56;
            int wo = wf + 3; if (wo >= 56) wo -= 56;
            orow = (size_t)bb * 3136 + ho * 56 + wo;
          }
#pragma unroll
          for (int nf = 0; nf < 4; ++nf) {
            int col = nb + nf * 16 + c;
            float val = acc[m][nf][i];
            if (EPI == 0) {
              float bv = bias[col] * (col < 1024 ? SCALE : 1.0f);
              ((short*)out)[(size_t)row * N + col] = f2bf(val + bv);
            } else if (EPI == 1) {
              ((float*)out)[orow * 1024 + col] = val + bias[col] + add0[orow * 1024 + col];
            } else if (EPI == 2) {
              float hv = val + bias[col];
              float z2 = 1.5957691216f * hv * (1.0f + 0.044715f * hv * hv);
              float th = 1.0f - 2.0f / (__expf(z2) + 1.0f);
              ((short*)out)[(size_t)row * N + col] = f2bf(0.5f * hv * (1.0f + th));
            } else {
              float res = add0[(size_t)row * 1024 + col];
              ((float*)out)[(size_t)row * 1024 + col] = val + bias[col] + res;
            }
          }
        }
      }
    }
    tau += G;
    if (tau >= ntot) break;
    bx = bxN; by = byN; AbC = AbN; BbC = BbN;
    int tau2 = tau + G; if (tau2 >= ntot) tau2 = tau;
    bxN = tau2 % ntm; byN = tau2 / ntm;
    AbN = A + (size_t)bxN * 256 * K;
    BbN = Bt + (size_t)byN * 256 * K;
#pragma unroll
    for (int m = 0; m < 8; ++m)
#pragma unroll
      for (int nf = 0; nf < 4; ++nf)
#pragma unroll
        for (int i = 0; i < 4; ++i) acc[m][nf][i] = 0.0f;
  }
#undef PHASE
#undef SB
#undef DSR_B4
#undef DSR_A
#undef STG
}

// ---------------- windowed attention: 1 wave = 1 (window, head); V direct from f32 input ----------------
__global__ __launch_bounds__(256) void attn_kernel(const short* __restrict__ qk,
                                                   const float* __restrict__ v,
                                                   const float* __restrict__ rpb,
                                                   short* __restrict__ ao) {
  __shared__ __align__(16) float rpbt[32 * 169];  // [head][idx]
  __shared__ int cnt[49];
  __shared__ __align__(16) short Vt[4][32 * 72];  // [wave][d][j] transposed V, padded
  __shared__ __align__(16) short Pl[4][64 * 72];  // [wave][row][col] P, padded
  int t = threadIdx.x, l = t & 63, w = t >> 6;
  int win = blockIdx.x >> 3;
  int h = (blockIdx.x & 7) * 4 + w;
  for (int e = t; e < 169 * 32; e += 256) {
    int hh = e / 169, idx = e - hh * 169;
    rpbt[e] = rpb[idx * 32 + hh];
  }
  if (t < 49) {
    int wi = win & 63;
    int hs = (wi >> 3) * 7 + t / 7, wsf = (wi & 7) * 7 + t % 7;
    int rh = hs < 49 ? 0 : (hs < 53 ? 1 : 2);
    int rw = wsf < 49 ? 0 : (wsf < 53 ? 1 : 2);
    cnt[t] = rh * 3 + rw;
  }
  if (l < 49) {
    int wi = win & 63, b = win >> 6;
    int hs = (wi >> 3) * 7 + l / 7, wsf = (wi & 7) * 7 + l % 7;
    int ho = hs + 3; if (ho >= 56) ho -= 56;
    int wo = wsf + 3; if (wo >= 56) wo -= 56;
    const float* vp = v + ((size_t)b * 3136 + ho * 56 + wo) * 1024 + h * 32;
#pragma unroll
    for (int d4 = 0; d4 < 8; ++d4) {
      f32x4 vv = *(const f32x4*)(vp + d4 * 4);
#pragma unroll
      for (int j = 0; j < 4; ++j) Vt[w][(d4 * 4 + j) * 72 + l] = f2bf(vv[j]);
    }
  } else {
#pragma unroll
    for (int d = 0; d < 32; ++d) Vt[w][d * 72 + l] = 0;
  }
  __syncthreads();
  int g = l >> 4, c = l & 15;
  bf16x8 qf[4], kf[4];
#pragma unroll
  for (int mt = 0; mt < 4; ++mt) {
    int r = mt * 16 + c; if (r > 48) r = 48;
    qf[mt] = *(const bf16x8*)&qk[((size_t)win * 49 + r) * 2048 + h * 32 + g * 8];
  }
#pragma unroll
  for (int nt = 0; nt < 4; ++nt) {
    int j = nt * 16 + c; if (j > 48) j = 48;
    kf[nt] = *(const bf16x8*)&qk[((size_t)win * 49 + j) * 2048 + 1024 + h * 32 + g * 8];
  }
  f32x4 s[4][4] = {};
#pragma unroll
  for (int mt = 0; mt < 4; ++mt)
#pragma unroll
    for (int nt = 0; nt < 4; ++nt)
      s[mt][nt] = __builtin_amdgcn_mfma_f32_16x16x32_bf16(qf[mt], kf[nt], s[mt][nt], 0, 0, 0);
#pragma unroll
  for (int mt = 0; mt < 4; ++mt)
#pragma unroll
    for (int nt = 0; nt < 4; ++nt)
#pragma unroll
      for (int i = 0; i < 4; ++i) {
        int r = mt * 16 + g * 4 + i;
        int j = nt * 16 + c;
        float val = s[mt][nt][i];
        if (r < 49 && j < 49) {
          int idx = (r / 7 - j / 7 + 6) * 13 + (r % 7 - j % 7 + 6);
          val += rpbt[h * 169 + idx];
          if (cnt[r] != cnt[j]) val -= 100.0f;
        } else {
          val = -1e30f;
        }
        s[mt][nt][i] = val;
      }
#pragma unroll
  for (int mt = 0; mt < 4; ++mt)
#pragma unroll
    for (int i = 0; i < 4; ++i) {
      float mx = s[mt][0][i];
#pragma unroll
      for (int nt = 1; nt < 4; ++nt) mx = fmaxf(mx, s[mt][nt][i]);
#pragma unroll
      for (int m2 = 1; m2 < 16; m2 <<= 1) mx = fmaxf(mx, __shfl_xor(mx, m2));
      float sum = 0.0f;
#pragma unroll
      for (int nt = 0; nt < 4; ++nt) {
        float e = __expf(s[mt][nt][i] - mx);
        s[mt][nt][i] = e;
        sum += e;
      }
#pragma unroll
      for (int m2 = 1; m2 < 16; m2 <<= 1) sum += __shfl_xor(sum, m2);
      float inv = 1.0f / sum;
#pragma unroll
      for (int nt = 0; nt < 4; ++nt) s[mt][nt][i] *= inv;
    }
#pragma unroll
  for (int mt = 0; mt < 4; ++mt)
#pragma unroll
    for (int nt = 0; nt < 4; ++nt)
#pragma unroll
      for (int i = 0; i < 4; ++i) {
        int r = mt * 16 + g * 4 + i, j = nt * 16 + c;
        Pl[w][r * 72 + j] = f2bf(s[mt][nt][i]);
      }
  __syncthreads();
  f32x4 o[4][2] = {};
#pragma unroll
  for (int kk = 0; kk < 2; ++kk) {
    bf16x8 vb[2];
#pragma unroll
    for (int n2 = 0; n2 < 2; ++n2)
      vb[n2] = *(const bf16x8*)&Vt[w][(n2 * 16 + c) * 72 + kk * 32 + g * 8];
#pragma unroll
    for (int mt = 0; mt < 4; ++mt) {
      bf16x8 pa = *(const bf16x8*)&Pl[w][(mt * 16 + c) * 72 + kk * 32 + g * 8];
#pragma unroll
      for (int n2 = 0; n2 < 2; ++n2)
        o[mt][n2] = __builtin_amdgcn_mfma_f32_16x16x32_bf16(pa, vb[n2], o[mt][n2], 0, 0, 0);
    }
  }
#pragma unroll
  for (int mt = 0; mt < 4; ++mt)
#pragma unroll
    for (int n2 = 0; n2 < 2; ++n2)
#pragma unroll
      for (int i = 0; i < 4; ++i) {
        int r = mt * 16 + g * 4 + i;
        if (r < 49) {
          int d = n2 * 16 + c;
          ao[((size_t)win * 49 + r) * 1024 + h * 32 + d] = f2bf(o[mt][n2][i]);
        }
      }
}

// ---------------- launch ----------------
extern "C" void kernel_launch(void* const* d_in, const int* in_sizes, int n_in,
                              void* d_out, int out_size, void* d_ws, size_t ws_size,
                              hipStream_t stream) {
  (void)in_sizes; (void)n_in; (void)out_size; (void)ws_size;
  const float* x = (const float*)d_in[0];
  const float* v = (const float*)d_in[1];
  const float* n1g = (const float*)d_in[3];
  const float* n1b = (const float*)d_in[4];
  const float* qkw = (const float*)d_in[5];
  const float* qkb = (const float*)d_in[6];
  const float* rpb = (const float*)d_in[7];
  const float* pjw = (const float*)d_in[8];
  const float* pjb = (const float*)d_in[9];
  const float* n2g = (const float*)d_in[10];
  const float* n2b = (const float*)d_in[11];
  const float* f1w = (const float*)d_in[12];
  const float* f1b = (const float*)d_in[13];
  const float* f2w = (const float*)d_in[14];
  const float* f2b = (const float*)d_in[15];
  char* ws = (char*)d_ws;
  // Peak workspace: ~169 MiB
  short* w_qk = (short*)(ws + 0);                    //  4.0 MB
  short* w_pj = (short*)(ws + 4194304);              //  2.0 MB
  short* w_f1 = (short*)(ws + 6291456);              //  8.0 MB
  short* w_f2 = (short*)(ws + 14680064);             //  8.0 MB
  short* xnw  = (short*)(ws + 23068672);             // 50 MB  [ln1 -> qk gemm]
  short* qkbuf= (short*)(ws + 74448896);             // 100 MB [qk gemm -> attn]
  short* aob  = (short*)(ws + 23068672);             // 50 MB  overlays xnw [attn -> proj]
  short* xn2  = (short*)(ws + 23068672);             // 50 MB  overlays aob [ln2 -> fc1]
  short* h1   = (short*)(ws + 74448896);             // 100 MB overlays qkbuf [fc1 -> fc2, per chunk]
  float* out = (float*)d_out;                        // also holds x2 (attn residual)

  cast_qkw_kernel<<<2048, 256, 0, stream>>>(qkw, w_qk);
  cast_kernel<<<1024, 256, 0, stream>>>(pjw, w_pj);
  cast_kernel<<<4096, 256, 0, stream>>>(f1w, w_f1);
  cast_kernel<<<4096, 256, 0, stream>>>(f2w, w_f2);
  ln1_permute_kernel<<<25088, 256, 0, stream>>>(x, n1g, n1b, xnw);
  gemmtb<0><<<512, 512, 0, stream>>>(xnw, w_qk, qkb, nullptr, qkbuf, 2048, 1024, 98, 784);
  attn_kernel<<<4096, 256, 0, stream>>>(qkbuf, v, rpb, aob);
  gemmtb<1><<<512, 512, 0, stream>>>(aob, w_pj, pjb, x, out, 1024, 1024, 98, 392);
  ln2_kernel<<<25088, 256, 0, stream>>>(out, n2g, n2b, xn2);
  // MLP in 2 M-chunks of 12544 rows (hidden buffer reuses dead qkbuf region)
  for (int ch = 0; ch < 2; ++ch) {
    const short* a1 = xn2 + (size_t)ch * 12544 * 1024;
    float* o2 = out + (size_t)ch * 12544 * 1024;
    gemmtb<2><<<512, 512, 0, stream>>>(a1, w_f1, f1b, nullptr, h1, 4096, 1024, 49, 784);
    gemmtb<3><<<512, 512, 0, stream>>>(h1, w_f2, f2b, o2, o2, 1024, 4096, 49, 196);
  }
}

// Round 14
// 1208.298 us; speedup vs baseline: 8.2971x; 8.2971x over previous
//
#include <hip/hip_runtime.h>
#include <math.h>

typedef __attribute__((ext_vector_type(8))) short bf16x8;
typedef __attribute__((ext_vector_type(4))) short short4v;
typedef __attribute__((ext_vector_type(4))) float f32x4;

#define SCALE 0.17677669529663687f  // 32^-0.5

__device__ __forceinline__ short f2bf(float f) {
  unsigned u = __builtin_bit_cast(unsigned, f);
  unsigned r = u + 0x7fffu + ((u >> 16) & 1u);
  return (short)(r >> 16);
}

// async global->LDS, 16B per lane (dest = wave-uniform base + lane*16)
__device__ __forceinline__ void gll16(const short* g, short* l) {
  __builtin_amdgcn_global_load_lds(
      (const __attribute__((address_space(1))) unsigned int*)g,
      (__attribute__((address_space(3))) unsigned int*)l, 16, 0, 0);
}

// ---------------- weight casts ----------------
__global__ __launch_bounds__(256) void cast_qkw_kernel(const float* __restrict__ src,
                                                       short* __restrict__ dst) {
  size_t i = (size_t)blockIdx.x * 256 + threadIdx.x;
  f32x4 v = *(const f32x4*)(src + i * 4);
  float sc = (i * 4 < (size_t)1024 * 1024) ? SCALE : 1.0f;  // q out-rows get scale
  short4v o;
#pragma unroll
  for (int j = 0; j < 4; ++j) o[j] = f2bf(v[j] * sc);
  *(short4v*)(dst + i * 4) = o;
}

__global__ __launch_bounds__(256) void cast_kernel(const float* __restrict__ src,
                                                   short* __restrict__ dst) {
  size_t i = (size_t)blockIdx.x * 256 + threadIdx.x;
  f32x4 v = *(const f32x4*)(src + i * 4);
  short4v o;
#pragma unroll
  for (int j = 0; j < 4; ++j) o[j] = f2bf(v[j]);
  *(short4v*)(dst + i * 4) = o;
}

// ---------------- LN1 + shift + window-partition ----------------
__global__ __launch_bounds__(256) void ln1_permute_kernel(
    const float* __restrict__ x,
    const float* __restrict__ g1, const float* __restrict__ b1,
    short* __restrict__ xnw) {
  int r = blockIdx.x;
  int b = r / 3136, rem = r % 3136;
  int wi = rem / 49, n = rem % 49;
  int hs = (wi >> 3) * 7 + n / 7, wsf = (wi & 7) * 7 + n % 7;
  int ho = hs + 3; if (ho >= 56) ho -= 56;
  int wo = wsf + 3; if (wo >= 56) wo -= 56;
  size_t src = ((size_t)b * 3136 + ho * 56 + wo) * 1024;
  int t = threadIdx.x;
  f32x4 xv = *(const f32x4*)(x + src + t * 4);
  float s = xv[0] + xv[1] + xv[2] + xv[3];
  float s2 = xv[0] * xv[0] + xv[1] * xv[1] + xv[2] * xv[2] + xv[3] * xv[3];
#pragma unroll
  for (int m = 1; m < 64; m <<= 1) { s += __shfl_xor(s, m); s2 += __shfl_xor(s2, m); }
  __shared__ float red[8];
  int w = t >> 6;
  if ((t & 63) == 0) { red[w * 2] = s; red[w * 2 + 1] = s2; }
  __syncthreads();
  float ts = red[0] + red[2] + red[4] + red[6];
  float ts2 = red[1] + red[3] + red[5] + red[7];
  float mu = ts * (1.0f / 1024.0f);
  float var = ts2 * (1.0f / 1024.0f) - mu * mu;
  float rs = rsqrtf(var + 1e-5f);
  short4v xo;
#pragma unroll
  for (int j = 0; j < 4; ++j) {
    int cc = t * 4 + j;
    xo[j] = f2bf((xv[j] - mu) * rs * g1[cc] + b1[cc]);
  }
  *(short4v*)(xnw + (size_t)r * 1024 + t * 4) = xo;
}

// ---------------- LN2 ----------------
__global__ __launch_bounds__(256) void ln2_kernel(const float* __restrict__ x2,
                                                  const float* __restrict__ g2,
                                                  const float* __restrict__ b2,
                                                  short* __restrict__ xn2) {
  int r = blockIdx.x;
  size_t src = (size_t)r * 1024;
  int t = threadIdx.x;
  f32x4 xv = *(const f32x4*)(x2 + src + t * 4);
  float s = xv[0] + xv[1] + xv[2] + xv[3];
  float s2 = xv[0] * xv[0] + xv[1] * xv[1] + xv[2] * xv[2] + xv[3] * xv[3];
#pragma unroll
  for (int m = 1; m < 64; m <<= 1) { s += __shfl_xor(s, m); s2 += __shfl_xor(s2, m); }
  __shared__ float red[8];
  int w = t >> 6;
  if ((t & 63) == 0) { red[w * 2] = s; red[w * 2 + 1] = s2; }
  __syncthreads();
  float ts = red[0] + red[2] + red[4] + red[6];
  float ts2 = red[1] + red[3] + red[5] + red[7];
  float mu = ts * (1.0f / 1024.0f);
  float var = ts2 * (1.0f / 1024.0f) - mu * mu;
  float rs = rsqrtf(var + 1e-5f);
  short4v xo;
#pragma unroll
  for (int j = 0; j < 4; ++j) {
    int cc = t * 4 + j;
    xo[j] = f2bf((xv[j] - mu) * rs * g2[cc] + b2[cc]);
  }
  *(short4v*)(xn2 + src + t * 4) = xo;
}

// ---------------- 256x256 persistent bf16 MFMA GEMM, ring-4 READ-BEHIND ----------------
// C[M,N] = A[M,K] @ Bt[N,K]^T. 512 threads = 8 waves (2M x 4N), per-wave 128x64 out.
// BK=32; ring-4 regions per matrix (region = K-step & 3, 16KiB each; LDS 128KiB).
// READ-BEHIND: phase p's MFMA consumes regs loaded at p-1; ds_reads for p+1 are issued
// AFTER the MFMA cluster -> wave-staggered LDS drain overlaps the MFMA pipe (r12 model:
// serial read->MFMA was 1130+1240 cyc/phase; overlap -> max(...)).
// Region lifecycle (stage-lead 3): staged p, vmcnt(4)-confirmed p+1, BAR(p+2)-collective,
// regs-read p+2, consumed p+3, re-staged p+4 (reads drained by p+3's counted MFMA wait
// before BAR(p+4)). Prologue stages steps 0-2, vmcnt(4)+BAR confirms 0,1. Persistent
// continuous K-step stream across tiles (NT multiple of 4). st_16x32 swizzle via
// pre-swizzled global source + swizzled ds_read; fragment-base bit9 lane-constant ->
// all ds_reads base+compile-time-imm.
// EPI: 0 = qk (bias, pre-scaled, bf16)  1 = proj (bias + shortcut, window->orig scatter, f32)
//      2 = fc1 (bias + tanh-gelu, bf16)  3 = fc2 (bias + residual, f32; add0 may alias out)
template <int EPI>
__global__ __launch_bounds__(512, 2) void gemm5(const short* __restrict__ A,
                                                const short* __restrict__ Bt,
                                                const float* __restrict__ bias,
                                                const float* __restrict__ add0,
                                                void* __restrict__ out, int N, int K,
                                                int ntm, int ntot) {
  __shared__ __align__(16) short lds[65536];  // 128 KiB: A regions 0..64K, B 64..128K
  char* basec = (char*)lds;
  int t = threadIdx.x;
  int l = t & 63;
  int w = t >> 6;
  int wm = w >> 2, wn = w & 3;
  int g = l >> 4, c = l & 15;
  int G = gridDim.x;
  // bijective XCD-chunked swizzle over the persistent grid
  int orig = blockIdx.x;
  int q = G >> 3, rr8 = G & 7, xcd = orig & 7, idx = orig >> 3;
  int tau = (xcd < rr8 ? xcd * (q + 1) : rr8 * (q + 1) + (xcd - rr8) * q) + idx;
  int bx = tau % ntm, by = tau / ntm;
  int tauN = tau + G; if (tauN >= ntot) tauN = tau;
  int bxN = tauN % ntm, byN = tauN / ntm;
  const short* AbC = A + (size_t)bx * 256 * K;
  const short* BbC = Bt + (size_t)by * 256 * K;
  const short* AbN = A + (size_t)bxN * 256 * K;
  const short* BbN = Bt + (size_t)byN * 256 * K;
  // staging source offsets (pre-swizzled st_16x32 inverse); region = [256 rows][32 cols]
  int o0 = t * 16, o1 = 8192 + t * 16;
  int ol0 = o0 ^ (((o0 >> 9) & 1) << 5);
  int ol1 = o1 ^ (((o1 >> 9) & 1) << 5);
  size_t off0 = (size_t)(ol0 >> 6) * K + ((ol0 & 63) >> 1);
  size_t off1 = (size_t)(ol1 >> 6) * K + ((ol1 & 63) >> 1);
  int NT = K >> 5;  // K-steps of 32 (32 or 128: multiple of 4)
  // fragment read bases (swizzle bit9 = (c&8)>>3, lane-constant; strides don't carry into bit5)
  int labA = (wm * 128 + c) * 64 + g * 16; labA ^= ((labA >> 9) & 1) << 5;
  int labB = (wn * 64 + c) * 64 + g * 16;  labB ^= ((labB >> 9) & 1) << 5;
  const char* pA = basec + labA;
  const char* pB = basec + 65536 + labB;

  f32x4 acc[8][4] = {};
  bf16x8 afX[8], bfX[4], afY[8], bfY[4];

#define STG(rr, rel_)                                                   \
  do {                                                                  \
    int rl = (rel_);                                                    \
    const short* bA = (rl < NT) ? AbC : AbN;                            \
    const short* bB = (rl < NT) ? BbC : BbN;                            \
    int tt = rl & (NT - 1);                                             \
    size_t kb = (size_t)tt * 32;                                        \
    short* rgA = (short*)(basec + (rr) * 16384);                        \
    short* rgB = (short*)(basec + 65536 + (rr) * 16384);                \
    gll16(bA + kb + off0, rgA + t * 8);                                 \
    gll16(bA + kb + off1, rgA + 4096 + t * 8);                          \
    gll16(bB + kb + off0, rgB + t * 8);                                 \
    gll16(bB + kb + off1, rgB + 4096 + t * 8);                          \
  } while (0)

#define DSR(SA, SBv, rr)                                                   \
  do {                                                                     \
    _Pragma("unroll") for (int m = 0; m < 8; ++m)                          \
      SA[m] = *(const bf16x8*)(pA + (rr) * 16384 + m * 1024);              \
    _Pragma("unroll") for (int nf = 0; nf < 4; ++nf)                       \
      SBv[nf] = *(const bf16x8*)(pB + (rr) * 16384 + nf * 1024);           \
  } while (0)

#define SB __builtin_amdgcn_sched_barrier(0)

// Phase j: BAR; MFMA(consume set, auto counted lgkm wait); READ next set <- region (j+1)&3;
// STG step s+j+3 -> region (j+3)&3; vmcnt(4).
#define PH(j, CA, CB, LA, LB)                                      \
  do {                                                             \
    SB;                                                            \
    __builtin_amdgcn_s_barrier();                                  \
    SB;                                                            \
    __builtin_amdgcn_s_setprio(1);                                 \
    _Pragma("unroll") for (int m = 0; m < 8; ++m)                  \
      _Pragma("unroll") for (int nf = 0; nf < 4; ++nf)             \
        acc[m][nf] = __builtin_amdgcn_mfma_f32_16x16x32_bf16(      \
            CA[m], CB[nf], acc[m][nf], 0, 0, 0);                   \
    __builtin_amdgcn_s_setprio(0);                                 \
    SB;                                                            \
    DSR(LA, LB, ((j) + 1) & 3);                                    \
    SB;                                                            \
    STG(((j) + 3) & 3, s + (j) + 3);                               \
    asm volatile("s_waitcnt vmcnt(4)" ::: "memory");                \
    SB;                                                            \
  } while (0)

  // prologue: stage steps 0,1,2 -> regions 0,1,2; confirm 0,1; read regs for phase 0
  STG(0, 0);
  STG(1, 1);
  STG(2, 2);
  asm volatile("s_waitcnt vmcnt(4)" ::: "memory");
  SB;
  __builtin_amdgcn_s_barrier();
  SB;
  DSR(afX, bfX, 0);

  while (true) {
    for (int s = 0; s < NT; s += 4) {
      PH(0, afX, bfX, afY, bfY);
      PH(1, afY, bfY, afX, bfX);
      PH(2, afX, bfX, afY, bfY);
      PH(3, afY, bfY, afX, bfX);
    }
    // ---- epilogue for current tile (regs for next tile's phase 0 already loaded) ----
    {
      int mb = bx * 256 + wm * 128;
      int nb = by * 256 + wn * 64;
#pragma unroll
      for (int m = 0; m < 8; ++m) {
#pragma unroll
        for (int i = 0; i < 4; ++i) {
          int row = mb + m * 16 + g * 4 + i;
          size_t orow = row;
          if (EPI == 1) {  // window order -> original order
            int bb = row / 3136, rem = row % 3136;
            int wi = rem / 49, n = rem % 49;
            int hs = (wi >> 3) * 7 + n / 7, wf = (wi & 7) * 7 + n % 7;
            int ho = hs + 3; if (ho >= 56) ho -= 56;
            int wo = wf + 3; if (wo >= 56) wo -= 56;
            orow = (size_t)bb * 3136 + ho * 56 + wo;
          }
#pragma unroll
          for (int nf = 0; nf < 4; ++nf) {
            int col = nb + nf * 16 + c;
            float val = acc[m][nf][i];
            if (EPI == 0) {
              float bv = bias[col] * (col < 1024 ? SCALE : 1.0f);
              ((short*)out)[(size_t)row * N + col] = f2bf(val + bv);
            } else if (EPI == 1) {
              ((float*)out)[orow * 1024 + col] = val + bias[col] + add0[orow * 1024 + col];
            } else if (EPI == 2) {
              float hv = val + bias[col];
              float z2 = 1.5957691216f * hv * (1.0f + 0.044715f * hv * hv);
              float th = 1.0f - 2.0f / (__expf(z2) + 1.0f);
              ((short*)out)[(size_t)row * N + col] = f2bf(0.5f * hv * (1.0f + th));
            } else {
              float res = add0[(size_t)row * 1024 + col];
              ((float*)out)[(size_t)row * 1024 + col] = val + bias[col] + res;
            }
          }
        }
      }
    }
    tau += G;
    if (tau >= ntot) break;
    bx = bxN; by = byN; AbC = AbN; BbC = BbN;
    int tau2 = tau + G; if (tau2 >= ntot) tau2 = tau;
    bxN = tau2 % ntm; byN = tau2 / ntm;
    AbN = A + (size_t)bxN * 256 * K;
    BbN = Bt + (size_t)byN * 256 * K;
#pragma unroll
    for (int m = 0; m < 8; ++m)
#pragma unroll
      for (int nf = 0; nf < 4; ++nf)
#pragma unroll
        for (int i = 0; i < 4; ++i) acc[m][nf][i] = 0.0f;
  }
#undef PH
#undef SB
#undef DSR
#undef STG
}

// ---------------- windowed attention: 1 wave = 1 (window, head); V direct from f32 input ----------------
__global__ __launch_bounds__(256) void attn_kernel(const short* __restrict__ qk,
                                                   const float* __restrict__ v,
                                                   const float* __restrict__ rpb,
                                                   short* __restrict__ ao) {
  __shared__ __align__(16) float rpbt[32 * 169];  // [head][idx]
  __shared__ int cnt[49];
  __shared__ __align__(16) short Vt[4][32 * 72];  // [wave][d][j] transposed V, padded
  __shared__ __align__(16) short Pl[4][64 * 72];  // [wave][row][col] P, padded
  int t = threadIdx.x, l = t & 63, w = t >> 6;
  int win = blockIdx.x >> 3;
  int h = (blockIdx.x & 7) * 4 + w;
  for (int e = t; e < 169 * 32; e += 256) {
    int hh = e / 169, idx = e - hh * 169;
    rpbt[e] = rpb[idx * 32 + hh];
  }
  if (t < 49) {
    int wi = win & 63;
    int hs = (wi >> 3) * 7 + t / 7, wsf = (wi & 7) * 7 + t % 7;
    int rh = hs < 49 ? 0 : (hs < 53 ? 1 : 2);
    int rw = wsf < 49 ? 0 : (wsf < 53 ? 1 : 2);
    cnt[t] = rh * 3 + rw;
  }
  if (l < 49) {
    int wi = win & 63, b = win >> 6;
    int hs = (wi >> 3) * 7 + l / 7, wsf = (wi & 7) * 7 + l % 7;
    int ho = hs + 3; if (ho >= 56) ho -= 56;
    int wo = wsf + 3; if (wo >= 56) wo -= 56;
    const float* vp = v + ((size_t)b * 3136 + ho * 56 + wo) * 1024 + h * 32;
#pragma unroll
    for (int d4 = 0; d4 < 8; ++d4) {
      f32x4 vv = *(const f32x4*)(vp + d4 * 4);
#pragma unroll
      for (int j = 0; j < 4; ++j) Vt[w][(d4 * 4 + j) * 72 + l] = f2bf(vv[j]);
    }
  } else {
#pragma unroll
    for (int d = 0; d < 32; ++d) Vt[w][d * 72 + l] = 0;
  }
  __syncthreads();
  int g = l >> 4, c = l & 15;
  bf16x8 qf[4], kf[4];
#pragma unroll
  for (int mt = 0; mt < 4; ++mt) {
    int r = mt * 16 + c; if (r > 48) r = 48;
    qf[mt] = *(const bf16x8*)&qk[((size_t)win * 49 + r) * 2048 + h * 32 + g * 8];
  }
#pragma unroll
  for (int nt = 0; nt < 4; ++nt) {
    int j = nt * 16 + c; if (j > 48) j = 48;
    kf[nt] = *(const bf16x8*)&qk[((size_t)win * 49 + j) * 2048 + 1024 + h * 32 + g * 8];
  }
  f32x4 s[4][4] = {};
#pragma unroll
  for (int mt = 0; mt < 4; ++mt)
#pragma unroll
    for (int nt = 0; nt < 4; ++nt)
      s[mt][nt] = __builtin_amdgcn_mfma_f32_16x16x32_bf16(qf[mt], kf[nt], s[mt][nt], 0, 0, 0);
#pragma unroll
  for (int mt = 0; mt < 4; ++mt)
#pragma unroll
    for (int nt = 0; nt < 4; ++nt)
#pragma unroll
      for (int i = 0; i < 4; ++i) {
        int r = mt * 16 + g * 4 + i;
        int j = nt * 16 + c;
        float val = s[mt][nt][i];
        if (r < 49 && j < 49) {
          int idx = (r / 7 - j / 7 + 6) * 13 + (r % 7 - j % 7 + 6);
          val += rpbt[h * 169 + idx];
          if (cnt[r] != cnt[j]) val -= 100.0f;
        } else {
          val = -1e30f;
        }
        s[mt][nt][i] = val;
      }
#pragma unroll
  for (int mt = 0; mt < 4; ++mt)
#pragma unroll
    for (int i = 0; i < 4; ++i) {
      float mx = s[mt][0][i];
#pragma unroll
      for (int nt = 1; nt < 4; ++nt) mx = fmaxf(mx, s[mt][nt][i]);
#pragma unroll
      for (int m2 = 1; m2 < 16; m2 <<= 1) mx = fmaxf(mx, __shfl_xor(mx, m2));
      float sum = 0.0f;
#pragma unroll
      for (int nt = 0; nt < 4; ++nt) {
        float e = __expf(s[mt][nt][i] - mx);
        s[mt][nt][i] = e;
        sum += e;
      }
#pragma unroll
      for (int m2 = 1; m2 < 16; m2 <<= 1) sum += __shfl_xor(sum, m2);
      float inv = 1.0f / sum;
#pragma unroll
      for (int nt = 0; nt < 4; ++nt) s[mt][nt][i] *= inv;
    }
#pragma unroll
  for (int mt = 0; mt < 4; ++mt)
#pragma unroll
    for (int nt = 0; nt < 4; ++nt)
#pragma unroll
      for (int i = 0; i < 4; ++i) {
        int r = mt * 16 + g * 4 + i, j = nt * 16 + c;
        Pl[w][r * 72 + j] = f2bf(s[mt][nt][i]);
      }
  __syncthreads();
  f32x4 o[4][2] = {};
#pragma unroll
  for (int kk = 0; kk < 2; ++kk) {
    bf16x8 vb[2];
#pragma unroll
    for (int n2 = 0; n2 < 2; ++n2)
      vb[n2] = *(const bf16x8*)&Vt[w][(n2 * 16 + c) * 72 + kk * 32 + g * 8];
#pragma unroll
    for (int mt = 0; mt < 4; ++mt) {
      bf16x8 pa = *(const bf16x8*)&Pl[w][(mt * 16 + c) * 72 + kk * 32 + g * 8];
#pragma unroll
      for (int n2 = 0; n2 < 2; ++n2)
        o[mt][n2] = __builtin_amdgcn_mfma_f32_16x16x32_bf16(pa, vb[n2], o[mt][n2], 0, 0, 0);
    }
  }
#pragma unroll
  for (int mt = 0; mt < 4; ++mt)
#pragma unroll
    for (int n2 = 0; n2 < 2; ++n2)
#pragma unroll
      for (int i = 0; i < 4; ++i) {
        int r = mt * 16 + g * 4 + i;
        if (r < 49) {
          int d = n2 * 16 + c;
          ao[((size_t)win * 49 + r) * 1024 + h * 32 + d] = f2bf(o[mt][n2][i]);
        }
      }
}

// ---------------- launch ----------------
extern "C" void kernel_launch(void* const* d_in, const int* in_sizes, int n_in,
                              void* d_out, int out_size, void* d_ws, size_t ws_size,
                              hipStream_t stream) {
  (void)in_sizes; (void)n_in; (void)out_size; (void)ws_size;
  const float* x = (const float*)d_in[0];
  const float* v = (const float*)d_in[1];
  const float* n1g = (const float*)d_in[3];
  const float* n1b = (const float*)d_in[4];
  const float* qkw = (const float*)d_in[5];
  const float* qkb = (const float*)d_in[6];
  const float* rpb = (const float*)d_in[7];
  const float* pjw = (const float*)d_in[8];
  const float* pjb = (const float*)d_in[9];
  const float* n2g = (const float*)d_in[10];
  const float* n2b = (const float*)d_in[11];
  const float* f1w = (const float*)d_in[12];
  const float* f1b = (const float*)d_in[13];
  const float* f2w = (const float*)d_in[14];
  const float* f2b = (const float*)d_in[15];
  char* ws = (char*)d_ws;
  // Peak workspace: ~169 MiB
  short* w_qk = (short*)(ws + 0);                    //  4.0 MB
  short* w_pj = (short*)(ws + 4194304);              //  2.0 MB
  short* w_f1 = (short*)(ws + 6291456);              //  8.0 MB
  short* w_f2 = (short*)(ws + 14680064);             //  8.0 MB
  short* xnw  = (short*)(ws + 23068672);             // 50 MB  [ln1 -> qk gemm]
  short* qkbuf= (short*)(ws + 74448896);             // 100 MB [qk gemm -> attn]
  short* aob  = (short*)(ws + 23068672);             // 50 MB  overlays xnw [attn -> proj]
  short* xn2  = (short*)(ws + 23068672);             // 50 MB  overlays aob [ln2 -> fc1]
  short* h1   = (short*)(ws + 74448896);             // 100 MB overlays qkbuf [fc1 -> fc2, per chunk]
  float* out = (float*)d_out;                        // also holds x2 (attn residual)

  cast_qkw_kernel<<<2048, 256, 0, stream>>>(qkw, w_qk);
  cast_kernel<<<1024, 256, 0, stream>>>(pjw, w_pj);
  cast_kernel<<<4096, 256, 0, stream>>>(f1w, w_f1);
  cast_kernel<<<4096, 256, 0, stream>>>(f2w, w_f2);
  ln1_permute_kernel<<<25088, 256, 0, stream>>>(x, n1g, n1b, xnw);
  gemm5<0><<<256, 512, 0, stream>>>(xnw, w_qk, qkb, nullptr, qkbuf, 2048, 1024, 98, 784);
  attn_kernel<<<4096, 256, 0, stream>>>(qkbuf, v, rpb, aob);
  gemm5<1><<<256, 512, 0, stream>>>(aob, w_pj, pjb, x, out, 1024, 1024, 98, 392);
  ln2_kernel<<<25088, 256, 0, stream>>>(out, n2g, n2b, xn2);
  // MLP in 2 M-chunks of 12544 rows (hidden buffer reuses dead qkbuf region)
  for (int ch = 0; ch < 2; ++ch) {
    const short* a1 = xn2 + (size_t)ch * 12544 * 1024;
    float* o2 = out + (size_t)ch * 12544 * 1024;
    gemm5<2><<<256, 512, 0, stream>>>(a1, w_f1, f1b, nullptr, h1, 4096, 1024, 49, 784);
    gemm5<3><<<196, 512, 0, stream>>>(h1, w_f2, f2b, o2, o2, 1024, 4096, 49, 196);
  }
}

// Round 15
// 982.043 us; speedup vs baseline: 10.2087x; 1.2304x over previous
//
#include <hip/hip_runtime.h>
#include <math.h>

typedef __attribute__((ext_vector_type(8))) short bf16x8;
typedef __attribute__((ext_vector_type(4))) short short4v;
typedef __attribute__((ext_vector_type(4))) float f32x4;

#define SCALE 0.17677669529663687f  // 32^-0.5

__device__ __forceinline__ short f2bf(float f) {
  unsigned u = __builtin_bit_cast(unsigned, f);
  unsigned r = u + 0x7fffu + ((u >> 16) & 1u);
  return (short)(r >> 16);
}

// async global->LDS, 16B per lane (dest = wave-uniform base + lane*16)
__device__ __forceinline__ void gll16(const short* g, short* l) {
  __builtin_amdgcn_global_load_lds(
      (const __attribute__((address_space(1))) unsigned int*)g,
      (__attribute__((address_space(3))) unsigned int*)l, 16, 0, 0);
}

// ---------------- weight casts ----------------
__global__ __launch_bounds__(256) void cast_qkw_kernel(const float* __restrict__ src,
                                                       short* __restrict__ dst) {
  size_t i = (size_t)blockIdx.x * 256 + threadIdx.x;
  f32x4 v = *(const f32x4*)(src + i * 4);
  float sc = (i * 4 < (size_t)1024 * 1024) ? SCALE : 1.0f;  // q out-rows get scale
  short4v o;
#pragma unroll
  for (int j = 0; j < 4; ++j) o[j] = f2bf(v[j] * sc);
  *(short4v*)(dst + i * 4) = o;
}

__global__ __launch_bounds__(256) void cast_kernel(const float* __restrict__ src,
                                                   short* __restrict__ dst) {
  size_t i = (size_t)blockIdx.x * 256 + threadIdx.x;
  f32x4 v = *(const f32x4*)(src + i * 4);
  short4v o;
#pragma unroll
  for (int j = 0; j < 4; ++j) o[j] = f2bf(v[j]);
  *(short4v*)(dst + i * 4) = o;
}

// ---------------- LN1 + shift + window-partition ----------------
__global__ __launch_bounds__(256) void ln1_permute_kernel(
    const float* __restrict__ x,
    const float* __restrict__ g1, const float* __restrict__ b1,
    short* __restrict__ xnw) {
  int r = blockIdx.x;
  int b = r / 3136, rem = r % 3136;
  int wi = rem / 49, n = rem % 49;
  int hs = (wi >> 3) * 7 + n / 7, wsf = (wi & 7) * 7 + n % 7;
  int ho = hs + 3; if (ho >= 56) ho -= 56;
  int wo = wsf + 3; if (wo >= 56) wo -= 56;
  size_t src = ((size_t)b * 3136 + ho * 56 + wo) * 1024;
  int t = threadIdx.x;
  f32x4 xv = *(const f32x4*)(x + src + t * 4);
  float s = xv[0] + xv[1] + xv[2] + xv[3];
  float s2 = xv[0] * xv[0] + xv[1] * xv[1] + xv[2] * xv[2] + xv[3] * xv[3];
#pragma unroll
  for (int m = 1; m < 64; m <<= 1) { s += __shfl_xor(s, m); s2 += __shfl_xor(s2, m); }
  __shared__ float red[8];
  int w = t >> 6;
  if ((t & 63) == 0) { red[w * 2] = s; red[w * 2 + 1] = s2; }
  __syncthreads();
  float ts = red[0] + red[2] + red[4] + red[6];
  float ts2 = red[1] + red[3] + red[5] + red[7];
  float mu = ts * (1.0f / 1024.0f);
  float var = ts2 * (1.0f / 1024.0f) - mu * mu;
  float rs = rsqrtf(var + 1e-5f);
  short4v xo;
#pragma unroll
  for (int j = 0; j < 4; ++j) {
    int cc = t * 4 + j;
    xo[j] = f2bf((xv[j] - mu) * rs * g1[cc] + b1[cc]);
  }
  *(short4v*)(xnw + (size_t)r * 1024 + t * 4) = xo;
}

// ---------------- LN2 ----------------
__global__ __launch_bounds__(256) void ln2_kernel(const float* __restrict__ x2,
                                                  const float* __restrict__ g2,
                                                  const float* __restrict__ b2,
                                                  short* __restrict__ xn2) {
  int r = blockIdx.x;
  size_t src = (size_t)r * 1024;
  int t = threadIdx.x;
  f32x4 xv = *(const f32x4*)(x2 + src + t * 4);
  float s = xv[0] + xv[1] + xv[2] + xv[3];
  float s2 = xv[0] * xv[0] + xv[1] * xv[1] + xv[2] * xv[2] + xv[3] * xv[3];
#pragma unroll
  for (int m = 1; m < 64; m <<= 1) { s += __shfl_xor(s, m); s2 += __shfl_xor(s2, m); }
  __shared__ float red[8];
  int w = t >> 6;
  if ((t & 63) == 0) { red[w * 2] = s; red[w * 2 + 1] = s2; }
  __syncthreads();
  float ts = red[0] + red[2] + red[4] + red[6];
  float ts2 = red[1] + red[3] + red[5] + red[7];
  float mu = ts * (1.0f / 1024.0f);
  float var = ts2 * (1.0f / 1024.0f) - mu * mu;
  float rs = rsqrtf(var + 1e-5f);
  short4v xo;
#pragma unroll
  for (int j = 0; j < 4; ++j) {
    int cc = t * 4 + j;
    xo[j] = f2bf((xv[j] - mu) * rs * g2[cc] + b2[cc]);
  }
  *(short4v*)(xn2 + src + t * 4) = xo;
}

// ---------------- 256x256 4-phase persistent bf16 MFMA GEMM (r12 best-known) ----------------
// C[M,N] = A[M,K] @ Bt[N,K]^T. 512 threads = 8 waves (2M x 4N), per-wave 128x64 out.
// PERSISTENT continuous K-step stream across tiles (one prologue per block).
// LDS 128KiB: 2 dbuf x {A ks0, A ks1, B ks0, B ks1} (16KiB regions), st_16x32 swizzle via
// pre-swizzled GLOBAL source + swizzled ds_read; fragment bases: swizzle bit9 lane-constant
// -> all ds_reads are base+imm. 4 barriers/iter; per phase: reads A(8)+B(4) -> stage 2
// regions (4 gll) -> vmcnt(4) -> barrier -> lgkmcnt(2) -> 16 MFMA -> lgkmcnt(0) -> 16 MFMA.
// EPI: 0 = qk (bias, pre-scaled, bf16)  1 = proj (bias + shortcut, window->orig scatter, f32)
//      2 = fc1 (bias + tanh-gelu, bf16)  3 = fc2 (bias + residual, f32; add0 may alias out)
template <int EPI>
__global__ __launch_bounds__(512, 2) void gemm4p(const short* __restrict__ A,
                                                 const short* __restrict__ Bt,
                                                 const float* __restrict__ bias,
                                                 const float* __restrict__ add0,
                                                 void* __restrict__ out, int N, int K,
                                                 int ntm, int ntot) {
  __shared__ __align__(16) short lds[65536];  // 128 KiB
  char* basec = (char*)lds;
  int t = threadIdx.x;
  int l = t & 63;
  int w = t >> 6;
  int wm = w >> 2, wn = w & 3;
  int g = l >> 4, c = l & 15;
  int G = gridDim.x;
  // bijective XCD-chunked swizzle over the persistent grid
  int orig = blockIdx.x;
  int q = G >> 3, rr8 = G & 7, xcd = orig & 7, idx = orig >> 3;
  int tau = (xcd < rr8 ? xcd * (q + 1) : rr8 * (q + 1) + (xcd - rr8) * q) + idx;
  int bx = tau % ntm, by = tau / ntm;
  int tauN = tau + G; if (tauN >= ntot) tauN = tau;
  int bxN = tauN % ntm, byN = tauN / ntm;
  const short* AbC = A + (size_t)bx * 256 * K;
  const short* BbC = Bt + (size_t)by * 256 * K;
  const short* AbN = A + (size_t)bxN * 256 * K;
  const short* BbN = Bt + (size_t)byN * 256 * K;
  // staging source offsets (pre-swizzled st_16x32 inverse), loop-invariant
  int o0 = t * 16, o1 = 8192 + t * 16;
  int ol0 = o0 ^ (((o0 >> 9) & 1) << 5);
  int ol1 = o1 ^ (((o1 >> 9) & 1) << 5);
  size_t off0 = (size_t)(ol0 >> 6) * K + ((ol0 & 63) >> 1);
  size_t off1 = (size_t)(ol1 >> 6) * K + ((ol1 & 63) >> 1);
  int NT = K >> 6;      // K-tiles of 64 per output tile (pow2)
  int NIH = NT >> 1;    // iterations per tile (2 K-tiles = 4 phases each)
  // fragment read bases: swizzle bit9 lane-constant -> base+imm for all reads
  int labA = (wm * 128 + c) * 64 + g * 16; labA ^= ((labA >> 9) & 1) << 5;
  int labB = (wn * 64 + c) * 64 + g * 16;  labB ^= ((labB >> 9) & 1) << 5;
  const char* pA0 = basec + labA;
  const char* pA1 = pA0 + 65536;
  const char* pB0 = basec + 32768 + labB;
  const char* pB1 = pB0 + 65536;

  f32x4 acc[8][4] = {};
  bf16x8 af[8], bf4[4];

#define STG(isA, sdb, sks, rel)                                               \
  do {                                                                        \
    int rl = (rel);                                                           \
    const short* bse = (rl < NT) ? ((isA) ? AbC : BbC) : ((isA) ? AbN : BbN); \
    int tt = rl & (NT - 1);                                                   \
    size_t kb = (size_t)tt * 64 + (sks) * 32;                                 \
    short* rg = (short*)(basec + (sdb) * 65536 + ((isA) ? 0 : 32768) + (sks) * 16384); \
    gll16(bse + kb + off0, rg + t * 8);                                       \
    gll16(bse + kb + off1, rg + 4096 + t * 8);                                \
  } while (0)

#define DSR_A(db, ks)                                                           \
  do {                                                                          \
    _Pragma("unroll") for (int m = 0; m < 8; ++m)                               \
      af[m] = *(const bf16x8*)(((db) ? pA1 : pA0) + (ks) * 16384 + m * 1024);   \
  } while (0)

#define DSR_B4(db, ks)                                                          \
  do {                                                                          \
    _Pragma("unroll") for (int nf = 0; nf < 4; ++nf)                            \
      bf4[nf] = *(const bf16x8*)(((db) ? pB1 : pB0) + (ks) * 16384 + nf * 1024); \
  } while (0)

#define SB __builtin_amdgcn_sched_barrier(0)

// Merged phase: compute (db,ks) fully (32 MFMA), stage {B(sB...), A(sA...)} = 4 gll.
// Reads issued first (A then B0..B3) so lgkmcnt(2) gates cluster1 (A+B0,B1).
#define PHASEQ(db, ks, sBdb, sBks, sBrel, sAdb, sAks, sArel)       \
  do {                                                             \
    DSR_A(db, ks);                                                 \
    DSR_B4(db, ks);                                                \
    STG(0, sBdb, sBks, sBrel);                                     \
    STG(1, sAdb, sAks, sArel);                                     \
    asm volatile("s_waitcnt vmcnt(4)" ::: "memory");               \
    SB;                                                            \
    __builtin_amdgcn_s_barrier();                                  \
    SB;                                                            \
    asm volatile("s_waitcnt lgkmcnt(2)" ::: "memory");             \
    SB;                                                            \
    __builtin_amdgcn_s_setprio(1);                                 \
    _Pragma("unroll") for (int m = 0; m < 8; ++m)                  \
      _Pragma("unroll") for (int n2 = 0; n2 < 2; ++n2)             \
        acc[m][n2] = __builtin_amdgcn_mfma_f32_16x16x32_bf16(      \
            af[m], bf4[n2], acc[m][n2], 0, 0, 0);                  \
    __builtin_amdgcn_s_setprio(0);                                 \
    SB;                                                            \
    asm volatile("s_waitcnt lgkmcnt(0)" ::: "memory");             \
    SB;                                                            \
    __builtin_amdgcn_s_setprio(1);                                 \
    _Pragma("unroll") for (int m = 0; m < 8; ++m)                  \
      _Pragma("unroll") for (int n2 = 2; n2 < 4; ++n2)             \
        acc[m][n2] = __builtin_amdgcn_mfma_f32_16x16x32_bf16(      \
            af[m], bf4[n2], acc[m][n2], 0, 0, 0);                  \
    __builtin_amdgcn_s_setprio(0);                                 \
  } while (0)

  // prologue: d0k0(A,B) first, then d0k1(A,B), d1k0(A); vmcnt(6) confirms d0k0
  STG(1, 0, 0, 0);
  STG(0, 0, 0, 0);
  STG(1, 0, 1, 0);
  STG(0, 0, 1, 0);
  STG(1, 1, 0, 1);
  asm volatile("s_waitcnt vmcnt(6)" ::: "memory");
  SB;
  __builtin_amdgcn_s_barrier();
  SB;

  while (true) {
    for (int iti = 0; iti < NIH; ++iti) {
      int s0 = 2 * iti;
      PHASEQ(0, 0, 1, 0, s0 + 1, 1, 1, s0 + 1);  // Q1: compute d0k0; stage B-d1k0(t1), A-d1k1(t1)
      PHASEQ(0, 1, 1, 1, s0 + 1, 0, 0, s0 + 2);  // Q2: compute d0k1; stage B-d1k1(t1), A-d0k0(t2)
      PHASEQ(1, 0, 0, 0, s0 + 2, 0, 1, s0 + 2);  // Q3: compute d1k0; stage B-d0k0(t2), A-d0k1(t2)
      PHASEQ(1, 1, 0, 1, s0 + 2, 1, 0, s0 + 3);  // Q4: compute d1k1; stage B-d0k1(t2), A-d1k0(t3)
    }
    // ---- epilogue for current tile ----
    {
      int mb = bx * 256 + wm * 128;
      int nb = by * 256 + wn * 64;
#pragma unroll
      for (int m = 0; m < 8; ++m) {
#pragma unroll
        for (int i = 0; i < 4; ++i) {
          int row = mb + m * 16 + g * 4 + i;
          size_t orow = row;
          if (EPI == 1) {  // window order -> original order
            int bb = row / 3136, rem = row % 3136;
            int wi = rem / 49, n = rem % 49;
            int hs = (wi >> 3) * 7 + n / 7, wf = (wi & 7) * 7 + n % 7;
            int ho = hs + 3; if (ho >= 56) ho -= 56;
            int wo = wf + 3; if (wo >= 56) wo -= 56;
            orow = (size_t)bb * 3136 + ho * 56 + wo;
          }
#pragma unroll
          for (int nf = 0; nf < 4; ++nf) {
            int col = nb + nf * 16 + c;
            float val = acc[m][nf][i];
            if (EPI == 0) {
              float bv = bias[col] * (col < 1024 ? SCALE : 1.0f);
              ((short*)out)[(size_t)row * N + col] = f2bf(val + bv);
            } else if (EPI == 1) {
              ((float*)out)[orow * 1024 + col] = val + bias[col] + add0[orow * 1024 + col];
            } else if (EPI == 2) {
              float hv = val + bias[col];
              float z2 = 1.5957691216f * hv * (1.0f + 0.044715f * hv * hv);
              float th = 1.0f - 2.0f / (__expf(z2) + 1.0f);
              ((short*)out)[(size_t)row * N + col] = f2bf(0.5f * hv * (1.0f + th));
            } else {
              float res = add0[(size_t)row * 1024 + col];
              ((float*)out)[(size_t)row * 1024 + col] = val + bias[col] + res;
            }
          }
        }
      }
    }
    tau += G;
    if (tau >= ntot) break;
    bx = bxN; by = byN; AbC = AbN; BbC = BbN;
    int tau2 = tau + G; if (tau2 >= ntot) tau2 = tau;
    bxN = tau2 % ntm; byN = tau2 / ntm;
    AbN = A + (size_t)bxN * 256 * K;
    BbN = Bt + (size_t)byN * 256 * K;
#pragma unroll
    for (int m = 0; m < 8; ++m)
#pragma unroll
      for (int nf = 0; nf < 4; ++nf)
#pragma unroll
        for (int i = 0; i < 4; ++i) acc[m][nf][i] = 0.0f;
  }
#undef PHASEQ
#undef SB
#undef DSR_B4
#undef DSR_A
#undef STG
}

// ---------------- windowed attention: 1 wave = 1 (window, head); V direct from f32 input ----------------
__global__ __launch_bounds__(256) void attn_kernel(const short* __restrict__ qk,
                                                   const float* __restrict__ v,
                                                   const float* __restrict__ rpb,
                                                   short* __restrict__ ao) {
  __shared__ __align__(16) float rpbt[32 * 169];  // [head][idx]
  __shared__ int cnt[49];
  __shared__ __align__(16) short Vt[4][32 * 72];  // [wave][d][j] transposed V, padded
  __shared__ __align__(16) short Pl[4][64 * 72];  // [wave][row][col] P, padded
  int t = threadIdx.x, l = t & 63, w = t >> 6;
  int win = blockIdx.x >> 3;
  int h = (blockIdx.x & 7) * 4 + w;
  for (int e = t; e < 169 * 32; e += 256) {
    int hh = e / 169, idx = e - hh * 169;
    rpbt[e] = rpb[idx * 32 + hh];
  }
  if (t < 49) {
    int wi = win & 63;
    int hs = (wi >> 3) * 7 + t / 7, wsf = (wi & 7) * 7 + t % 7;
    int rh = hs < 49 ? 0 : (hs < 53 ? 1 : 2);
    int rw = wsf < 49 ? 0 : (wsf < 53 ? 1 : 2);
    cnt[t] = rh * 3 + rw;
  }
  if (l < 49) {
    int wi = win & 63, b = win >> 6;
    int hs = (wi >> 3) * 7 + l / 7, wsf = (wi & 7) * 7 + l % 7;
    int ho = hs + 3; if (ho >= 56) ho -= 56;
    int wo = wsf + 3; if (wo >= 56) wo -= 56;
    const float* vp = v + ((size_t)b * 3136 + ho * 56 + wo) * 1024 + h * 32;
#pragma unroll
    for (int d4 = 0; d4 < 8; ++d4) {
      f32x4 vv = *(const f32x4*)(vp + d4 * 4);
#pragma unroll
      for (int j = 0; j < 4; ++j) Vt[w][(d4 * 4 + j) * 72 + l] = f2bf(vv[j]);
    }
  } else {
#pragma unroll
    for (int d = 0; d < 32; ++d) Vt[w][d * 72 + l] = 0;
  }
  __syncthreads();
  int g = l >> 4, c = l & 15;
  bf16x8 qf[4], kf[4];
#pragma unroll
  for (int mt = 0; mt < 4; ++mt) {
    int r = mt * 16 + c; if (r > 48) r = 48;
    qf[mt] = *(const bf16x8*)&qk[((size_t)win * 49 + r) * 2048 + h * 32 + g * 8];
  }
#pragma unroll
  for (int nt = 0; nt < 4; ++nt) {
    int j = nt * 16 + c; if (j > 48) j = 48;
    kf[nt] = *(const bf16x8*)&qk[((size_t)win * 49 + j) * 2048 + 1024 + h * 32 + g * 8];
  }
  f32x4 s[4][4] = {};
#pragma unroll
  for (int mt = 0; mt < 4; ++mt)
#pragma unroll
    for (int nt = 0; nt < 4; ++nt)
      s[mt][nt] = __builtin_amdgcn_mfma_f32_16x16x32_bf16(qf[mt], kf[nt], s[mt][nt], 0, 0, 0);
#pragma unroll
  for (int mt = 0; mt < 4; ++mt)
#pragma unroll
    for (int nt = 0; nt < 4; ++nt)
#pragma unroll
      for (int i = 0; i < 4; ++i) {
        int r = mt * 16 + g * 4 + i;
        int j = nt * 16 + c;
        float val = s[mt][nt][i];
        if (r < 49 && j < 49) {
          int idx = (r / 7 - j / 7 + 6) * 13 + (r % 7 - j % 7 + 6);
          val += rpbt[h * 169 + idx];
          if (cnt[r] != cnt[j]) val -= 100.0f;
        } else {
          val = -1e30f;
        }
        s[mt][nt][i] = val;
      }
#pragma unroll
  for (int mt = 0; mt < 4; ++mt)
#pragma unroll
    for (int i = 0; i < 4; ++i) {
      float mx = s[mt][0][i];
#pragma unroll
      for (int nt = 1; nt < 4; ++nt) mx = fmaxf(mx, s[mt][nt][i]);
#pragma unroll
      for (int m2 = 1; m2 < 16; m2 <<= 1) mx = fmaxf(mx, __shfl_xor(mx, m2));
      float sum = 0.0f;
#pragma unroll
      for (int nt = 0; nt < 4; ++nt) {
        float e = __expf(s[mt][nt][i] - mx);
        s[mt][nt][i] = e;
        sum += e;
      }
#pragma unroll
      for (int m2 = 1; m2 < 16; m2 <<= 1) sum += __shfl_xor(sum, m2);
      float inv = 1.0f / sum;
#pragma unroll
      for (int nt = 0; nt < 4; ++nt) s[mt][nt][i] *= inv;
    }
#pragma unroll
  for (int mt = 0; mt < 4; ++mt)
#pragma unroll
    for (int nt = 0; nt < 4; ++nt)
#pragma unroll
      for (int i = 0; i < 4; ++i) {
        int r = mt * 16 + g * 4 + i, j = nt * 16 + c;
        Pl[w][r * 72 + j] = f2bf(s[mt][nt][i]);
      }
  __syncthreads();
  f32x4 o[4][2] = {};
#pragma unroll
  for (int kk = 0; kk < 2; ++kk) {
    bf16x8 vb[2];
#pragma unroll
    for (int n2 = 0; n2 < 2; ++n2)
      vb[n2] = *(const bf16x8*)&Vt[w][(n2 * 16 + c) * 72 + kk * 32 + g * 8];
#pragma unroll
    for (int mt = 0; mt < 4; ++mt) {
      bf16x8 pa = *(const bf16x8*)&Pl[w][(mt * 16 + c) * 72 + kk * 32 + g * 8];
#pragma unroll
      for (int n2 = 0; n2 < 2; ++n2)
        o[mt][n2] = __builtin_amdgcn_mfma_f32_16x16x32_bf16(pa, vb[n2], o[mt][n2], 0, 0, 0);
    }
  }
#pragma unroll
  for (int mt = 0; mt < 4; ++mt)
#pragma unroll
    for (int n2 = 0; n2 < 2; ++n2)
#pragma unroll
      for (int i = 0; i < 4; ++i) {
        int r = mt * 16 + g * 4 + i;
        if (r < 49) {
          int d = n2 * 16 + c;
          ao[((size_t)win * 49 + r) * 1024 + h * 32 + d] = f2bf(o[mt][n2][i]);
        }
      }
}

// ---------------- launch ----------------
extern "C" void kernel_launch(void* const* d_in, const int* in_sizes, int n_in,
                              void* d_out, int out_size, void* d_ws, size_t ws_size,
                              hipStream_t stream) {
  (void)in_sizes; (void)n_in; (void)out_size; (void)ws_size;
  const float* x = (const float*)d_in[0];
  const float* v = (const float*)d_in[1];
  const float* n1g = (const float*)d_in[3];
  const float* n1b = (const float*)d_in[4];
  const float* qkw = (const float*)d_in[5];
  const float* qkb = (const float*)d_in[6];
  const float* rpb = (const float*)d_in[7];
  const float* pjw = (const float*)d_in[8];
  const float* pjb = (const float*)d_in[9];
  const float* n2g = (const float*)d_in[10];
  const float* n2b = (const float*)d_in[11];
  const float* f1w = (const float*)d_in[12];
  const float* f1b = (const float*)d_in[13];
  const float* f2w = (const float*)d_in[14];
  const float* f2b = (const float*)d_in[15];
  char* ws = (char*)d_ws;
  // Peak workspace: ~169 MiB
  short* w_qk = (short*)(ws + 0);                    //  4.0 MB
  short* w_pj = (short*)(ws + 4194304);              //  2.0 MB
  short* w_f1 = (short*)(ws + 6291456);              //  8.0 MB
  short* w_f2 = (short*)(ws + 14680064);             //  8.0 MB
  short* xnw  = (short*)(ws + 23068672);             // 50 MB  [ln1 -> qk gemm]
  short* qkbuf= (short*)(ws + 74448896);             // 100 MB [qk gemm -> attn]
  short* aob  = (short*)(ws + 23068672);             // 50 MB  overlays xnw [attn -> proj]
  short* xn2  = (short*)(ws + 23068672);             // 50 MB  overlays aob [ln2 -> fc1]
  short* h1   = (short*)(ws + 74448896);             // 100 MB overlays qkbuf [fc1 -> fc2, per chunk]
  float* out = (float*)d_out;                        // also holds x2 (attn residual)

  cast_qkw_kernel<<<2048, 256, 0, stream>>>(qkw, w_qk);
  cast_kernel<<<1024, 256, 0, stream>>>(pjw, w_pj);
  cast_kernel<<<4096, 256, 0, stream>>>(f1w, w_f1);
  cast_kernel<<<4096, 256, 0, stream>>>(f2w, w_f2);
  ln1_permute_kernel<<<25088, 256, 0, stream>>>(x, n1g, n1b, xnw);
  gemm4p<0><<<256, 512, 0, stream>>>(xnw, w_qk, qkb, nullptr, qkbuf, 2048, 1024, 98, 784);
  attn_kernel<<<4096, 256, 0, stream>>>(qkbuf, v, rpb, aob);
  gemm4p<1><<<256, 512, 0, stream>>>(aob, w_pj, pjb, x, out, 1024, 1024, 98, 392);
  ln2_kernel<<<25088, 256, 0, stream>>>(out, n2g, n2b, xn2);
  // MLP in 2 M-chunks of 12544 rows (hidden buffer reuses dead qkbuf region)
  for (int ch = 0; ch < 2; ++ch) {
    const short* a1 = xn2 + (size_t)ch * 12544 * 1024;
    float* o2 = out + (size_t)ch * 12544 * 1024;
    gemm4p<2><<<256, 512, 0, stream>>>(a1, w_f1, f1b, nullptr, h1, 4096, 1024, 49, 784);
    gemm4p<3><<<196, 512, 0, stream>>>(h1, w_f2, f2b, o2, o2, 1024, 4096, 49, 196);
  }
}